// Round 6
// baseline (165.341 us; speedup 1.0000x reference)
//
#include <hip/hip_runtime.h>
#include <math.h>

#define B_ 8
#define T_ 2048
#define D_ 1024
#define H_ 128
#define BT (B_ * T_)

typedef short bf16x8 __attribute__((ext_vector_type(8)));
typedef float f32x4 __attribute__((ext_vector_type(4)));

static constexpr float SCALE = 0.08838834764831845f;  // 1/sqrt(128)

__device__ inline unsigned short f2b(float f) {
  unsigned int u = __float_as_uint(f);
  u += 0x7FFF + ((u >> 16) & 1);  // RNE
  return (unsigned short)(u >> 16);
}
__device__ inline unsigned int pk2(float a, float b) {
  return (unsigned int)f2b(a) | ((unsigned int)f2b(b) << 16);
}

// global (AS1) -> LDS (AS3) direct 16B copy; dest = wave-uniform base + lane*16
__device__ __forceinline__ void gll16(const void* g, void* l) {
  __builtin_amdgcn_global_load_lds(
      (const __attribute__((address_space(1))) void*)g,
      (__attribute__((address_space(3))) void*)l, 16, 0, 0);
}

// ---------------------------------------------------------------------------
// Setup: W[d][h] fp32 -> Wt[sel][h][d] bf16 through LDS, coalesced stores.
// ---------------------------------------------------------------------------
__global__ __launch_bounds__(256) void wcvt_kernel(
    const float* __restrict__ Wq, const float* __restrict__ Wk,
    const float* __restrict__ Wv, short* __restrict__ Wt) {
  __shared__ short Wls[128 * 72];  // [h][d] bf16, pitch 72
  const int sel = blockIdx.y;
  const float* W = sel == 0 ? Wq : (sel == 1 ? Wk : Wv);
  const int d0 = blockIdx.x * 64;
  const int tid = threadIdx.x;
#pragma unroll
  for (int i = 0; i < 8; ++i) {
    int slot = tid + i * 256;         // 2048 float4 slots: 64 d x 32 h-groups
    int r = slot >> 5, hg = slot & 31;
    float4 w = *(const float4*)(W + (size_t)(d0 + r) * H_ + hg * 4);
    Wls[(hg * 4 + 0) * 72 + r] = (short)f2b(w.x);
    Wls[(hg * 4 + 1) * 72 + r] = (short)f2b(w.y);
    Wls[(hg * 4 + 2) * 72 + r] = (short)f2b(w.z);
    Wls[(hg * 4 + 3) * 72 + r] = (short)f2b(w.w);
  }
  __syncthreads();
  short* dst = Wt + (size_t)sel * D_ * H_;
#pragma unroll
  for (int i = 0; i < 4; ++i) {
    int slot = tid + i * 256;         // 1024 int4 slots: 128 h x 8 d-groups
    int h = slot >> 3, g = slot & 7;
    *(int4*)(dst + (size_t)h * D_ + d0 + g * 8) = *(int4*)&Wls[h * 72 + g * 8];
  }
}

// ---------------------------------------------------------------------------
// Proj (v2, FUSED): one kernel computes q, k, v — x is read ONCE from HBM
// (the old (256,3) grid read the 64 MB x three times: ~192 MB = ~30 µs
// HBM-bound floor; fused floor is ~76 MB = ~12 µs).
// Per block: 64 rows x 384 cols (q|k|v). Wt is contiguous [384][1024] bf16
// (sel folds into the row index n; same XOR swizzle keyed on n&7).
// LDS: Xs dbuf 16 KB + Ws dbuf 96 KB = 112 KB -> 1 block/CU, grid 256 =
// whole grid co-resident. acc[3][2][4] = 96 VGPRs; 48 MFMA per k-step.
// ---------------------------------------------------------------------------
__global__ __launch_bounds__(256, 1) void proj_kernel(
    const float* __restrict__ x, const short* __restrict__ Wt,
    short* __restrict__ qb, short* __restrict__ kb, short* __restrict__ vtb) {
  __shared__ alignas(16) char smem[114688];
  short* Xs0 = (short*)smem;             // [64][64] bf16 swizzled, 8 KB
  short* Xs1 = (short*)(smem + 8192);
  short* Ws0 = (short*)(smem + 16384);   // [384][64] bf16 swizzled, 48 KB
  short* Ws1 = (short*)(smem + 65536);

  const int tid = threadIdx.x;
  const int wave = tid >> 6, lane = tid & 63;
  const int ln = lane & 15, quad = lane >> 4;
  const int mw = wave & 1, nw = wave >> 1;  // wave tile: 32 rows x 64 cols/sel
  const int row0 = blockIdx.x * 64;

  f32x4 acc[3][2][4];
#pragma unroll
  for (int sel = 0; sel < 3; ++sel)
#pragma unroll
    for (int mi = 0; mi < 2; ++mi)
#pragma unroll
      for (int ni = 0; ni < 4; ++ni) acc[sel][mi][ni] = (f32x4){0.f, 0.f, 0.f, 0.f};

  auto stage = [&](int bf, int k0) {
    short* Ws = bf ? Ws1 : Ws0;
    // 384 W-rows (q|k|v), 12 gll rounds: each wave covers 96 rows
#pragma unroll
    for (int j = 0; j < 12; ++j) {
      const int rbase = wave * 96 + j * 8;
      const int n = rbase + (lane >> 3);
      const int gp = (lane & 7) ^ (n & 7);
      gll16(Wt + (size_t)n * D_ + k0 + gp * 8, (char*)Ws + rbase * 128);
    }
    short* Xs = bf ? Xs1 : Xs0;
    float4 xr[4];
#pragma unroll
    for (int i = 0; i < 4; ++i) {
      int fid = tid + i * 256;           // 1024 float4 slots: 64 rows x 16
      int r = fid >> 4, g4 = fid & 15;
      xr[i] = *(const float4*)(x + (size_t)(row0 + r) * D_ + k0 + g4 * 4);
    }
#pragma unroll
    for (int i = 0; i < 4; ++i) {
      int fid = tid + i * 256;
      int r = fid >> 4, g4 = fid & 15;
      int g = g4 >> 1, half = g4 & 1;
      unsigned int* p = (unsigned int*)&Xs[r * 64 + ((g ^ (r & 7)) * 8) + half * 4];
      p[0] = pk2(xr[i].x, xr[i].y);
      p[1] = pk2(xr[i].z, xr[i].w);
    }
  };

  stage(0, 0);  // prologue
  for (int s = 0; s < 16; ++s) {
    __syncthreads();  // drains buf[s&1] (gll + ds_write); prev compute done
    if (s < 15) stage((s + 1) & 1, (s + 1) * 64);
    const short* Xs = (s & 1) ? Xs1 : Xs0;
    const short* Ws = (s & 1) ? Ws1 : Ws0;
#pragma unroll
    for (int kk = 0; kk < 2; ++kk) {
      bf16x8 a[2];
#pragma unroll
      for (int mi = 0; mi < 2; ++mi) {
        int r = mw * 32 + mi * 16 + ln;
        a[mi] = *(bf16x8*)&Xs[r * 64 + (((kk * 4 + quad) ^ (r & 7)) * 8)];
      }
#pragma unroll
      for (int sel = 0; sel < 3; ++sel) {
#pragma unroll
        for (int ni = 0; ni < 4; ++ni) {
          int n = sel * 128 + nw * 64 + ni * 16 + ln;
          bf16x8 bb = *(bf16x8*)&Ws[n * 64 + (((kk * 4 + quad) ^ (n & 7)) * 8)];
#pragma unroll
          for (int mi = 0; mi < 2; ++mi)
            acc[sel][mi][ni] = __builtin_amdgcn_mfma_f32_16x16x32_bf16(
                a[mi], bb, acc[sel][mi][ni], 0, 0, 0);
        }
      }
    }
  }

  __syncthreads();  // tiles dead; reuse smem for epilogue repack
  short* Cs = (short*)smem;
  // --- q, k: row-major [BT][128] through 136-pitch transpose ---
#pragma unroll
  for (int sel = 0; sel < 2; ++sel) {
    short* out = sel ? kb : qb;
#pragma unroll
    for (int mi = 0; mi < 2; ++mi)
#pragma unroll
      for (int ni = 0; ni < 4; ++ni)
#pragma unroll
        for (int rr = 0; rr < 4; ++rr)
          Cs[(mw * 32 + mi * 16 + quad * 4 + rr) * 136 + nw * 64 + ni * 16 + ln] =
              (short)f2b(acc[sel][mi][ni][rr]);
    __syncthreads();
#pragma unroll
    for (int i = 0; i < 4; ++i) {
      int slot = tid + i * 256;          // 1024 int4 slots: 64 rows x 16
      int r = slot >> 4, g = slot & 15;
      *(int4*)(out + (size_t)(row0 + r) * H_ + g * 8) = *(int4*)&Cs[r * 136 + g * 8];
    }
    __syncthreads();
  }
  // --- v: transposed [B][128][T] through 72-pitch repack ---
#pragma unroll
  for (int mi = 0; mi < 2; ++mi)
#pragma unroll
    for (int ni = 0; ni < 4; ++ni)
#pragma unroll
      for (int rr = 0; rr < 4; ++rr)
        Cs[(nw * 64 + ni * 16 + ln) * 72 + mw * 32 + mi * 16 + quad * 4 + rr] =
            (short)f2b(acc[2][mi][ni][rr]);
  __syncthreads();
  const int b = row0 >> 11, t0 = row0 & 2047;
#pragma unroll
  for (int i = 0; i < 4; ++i) {
    int slot = tid + i * 256;            // 1024 int4 slots: 128 h x 8
    int h = slot >> 3, g = slot & 7;
    *(int4*)(vtb + (size_t)(b * H_ + h) * T_ + t0 + g * 8) = *(int4*)&Cs[h * 72 + g * 8];
  }
}

// ---------------------------------------------------------------------------
// Attention part 1 (v5, unchanged this round): 32-key chunks, K+V LDS dbuf
// via gll, one barrier per chunk, 4 blocks/CU, defer-max, XCD affinity.
// ---------------------------------------------------------------------------
__global__ __launch_bounds__(256, 4) void attn_part(
    const short* __restrict__ qb, const short* __restrict__ kb,
    const short* __restrict__ vtb, float* __restrict__ po,
    float* __restrict__ pm, float* __restrict__ pl) {
  __shared__ alignas(16) char smem[37376];
  short* Ks0 = (short*)smem;               // [32][128] bf16 swizzled, 8 KB
  short* Ks1 = (short*)(smem + 8192);
  short* Vt0 = (short*)(smem + 16384);     // [128][32] bf16 swizzled, 8 KB
  short* Vt1 = (short*)(smem + 24576);
  short* Pt  = (short*)(smem + 32768);     // 4 waves x [16][36] bf16, 4.5 KB

  const int tid = threadIdx.x;
  const int wv = tid >> 6, lane = tid & 63;
  const int ln = lane & 15, quad = lane >> 4;
  const int b = blockIdx.x & 7;            // XCD-affinity: xcd = id % 8 = b
  const int rr = 79 - (blockIdx.x >> 3);   // heavy segments first
  // decode rr -> (j, s):  group g = j>>3 has nseg g+1; cum base 4g(g+1)
  const int g = (rr >= 48) ? 3 : (rr >= 24) ? 2 : (rr >= 8) ? 1 : 0;
  const int local = rr - 4 * g * (g + 1);
  const int j = 8 * g + local / (g + 1);
  const int s = local - (local / (g + 1)) * (g + 1);
  const int sid = b * 80 + rr;             // partial storage slot
  const int q0 = j * 64;
  const int nchunks = min(16, 2 * (j + 1) - 16 * s);  // 32-key chunks

  short* myP = Pt + wv * (16 * 36);
  const int qglob = q0 + wv * 16 + ln;

  bf16x8 qfr[4];  // this wave's 16 queries, B-operand layout
#pragma unroll
  for (int kk = 0; kk < 4; ++kk)
    qfr[kk] = *(const bf16x8*)(qb + (size_t)(b * T_ + q0 + wv * 16 + ln) * H_ +
                               kk * 32 + quad * 8);

  f32x4 oacc[8];  // O^T: h = ht*16+quad*4+r, q = ln
#pragma unroll
  for (int ht = 0; ht < 8; ++ht) oacc[ht] = (f32x4){0.f, 0.f, 0.f, 0.f};

  float m_run = -INFINITY, l_run = 0.f;

  auto stageK = [&](short* dst, int s0) {
#pragma unroll
    for (int jj = 0; jj < 2; ++jj) {
      const int rb = wv * 8 + jj * 4;        // 8 rows per wave (32 total)
      const int r = rb + (lane >> 4);
      const int gp = (lane & 15) ^ (r & 7);
      gll16(kb + (size_t)(b * T_ + s0 + r) * H_ + gp * 8, (char*)dst + rb * 256);
    }
  };
  auto stageV = [&](short* dst, int s0) {
#pragma unroll
    for (int jj = 0; jj < 2; ++jj) {
      const int hb = wv * 32 + jj * 16;      // 32 rows per wave (128 total)
      const int h = hb + (lane >> 2);
      const int gp = (lane & 3) ^ (h & 3) ^ ((h >> 2) & 3);
      gll16(vtb + (size_t)(b * H_ + h) * T_ + s0 + gp * 8, (char*)dst + hb * 64);
    }
  };

  stageK(Ks0, 512 * s);  // prologue: first 32-key chunk of this segment
  stageV(Vt0, 512 * s);

  for (int ch = 0; ch < nchunks; ++ch) {
    const int s0 = 512 * s + ch * 32;
    const int cur = ch & 1;
    __syncthreads();  // drains gll for buf[cur]; other buffer free to restage
    if (ch + 1 < nchunks) {
      stageK(cur ? Ks0 : Ks1, s0 + 32);
      stageV(cur ? Vt0 : Vt1, s0 + 32);
    }
    const short* Kc = cur ? Ks1 : Ks0;
    const short* Vc = cur ? Vt1 : Vt0;

    // S^T = K * Q^T : 2 key-tiles x 4 kk = 8 MFMAs (per wave, its 16 q)
    f32x4 sacc[2];
#pragma unroll
    for (int t = 0; t < 2; ++t) sacc[t] = (f32x4){0.f, 0.f, 0.f, 0.f};
#pragma unroll
    for (int kk = 0; kk < 4; ++kk) {
#pragma unroll
      for (int t = 0; t < 2; ++t) {
        const int krow = t * 16 + ln;
        bf16x8 kf = *(bf16x8*)&Kc[krow * 128 + (((kk * 4 + quad) ^ (krow & 7)) * 8)];
        sacc[t] = __builtin_amdgcn_mfma_f32_16x16x32_bf16(kf, qfr[kk], sacc[t], 0, 0, 0);
      }
    }

    // wave-local online softmax over 32 keys
    float sv[2][4];
    float mc = -INFINITY;
    if (s0 + 31 <= q0 + wv * 16) {  // chunk fully visible for this wave
#pragma unroll
      for (int t = 0; t < 2; ++t)
#pragma unroll
        for (int r = 0; r < 4; ++r) {
          sv[t][r] = sacc[t][r] * SCALE;
          mc = fmaxf(mc, sv[t][r]);
        }
    } else {
#pragma unroll
      for (int t = 0; t < 2; ++t)
#pragma unroll
        for (int r = 0; r < 4; ++r) {
          const int key = s0 + t * 16 + quad * 4 + r;
          float sc = sacc[t][r] * SCALE;
          sv[t][r] = (key <= qglob) ? sc : -INFINITY;
          mc = fmaxf(mc, sv[t][r]);
        }
    }
    mc = fmaxf(mc, __shfl_xor(mc, 16));
    mc = fmaxf(mc, __shfl_xor(mc, 32));

    // defer-max (T13): skip the O-rescale unless the max grew by > 8.
    // (-inf chunks: mc=-inf <= m_run+8 even at m_run=-inf -> skip, p=0.)
    if (!__all(mc <= m_run + 8.f)) {
      const float mnew = fmaxf(m_run, mc);
      const float alpha = __expf(m_run - mnew);
#pragma unroll
      for (int ht = 0; ht < 8; ++ht)
#pragma unroll
        for (int r = 0; r < 4; ++r) oacc[ht][r] *= alpha;
      l_run *= alpha;
      m_run = mnew;
    }
    float lc = 0.f;
    float p[2][4];
#pragma unroll
    for (int t = 0; t < 2; ++t)
#pragma unroll
      for (int r = 0; r < 4; ++r) {
        p[t][r] = __expf(sv[t][r] - m_run);
        lc += p[t][r];
      }
    lc += __shfl_xor(lc, 16);
    lc += __shfl_xor(lc, 32);
    l_run += lc;

    // P^T -> wave-private LDS scratch (same-wave lgkm-ordered; no barrier)
#pragma unroll
    for (int t = 0; t < 2; ++t) {
      *(unsigned int*)&myP[ln * 36 + t * 16 + quad * 4 + 0] = pk2(p[t][0], p[t][1]);
      *(unsigned int*)&myP[ln * 36 + t * 16 + quad * 4 + 2] = pk2(p[t][2], p[t][3]);
    }

    // O^T += V^T * P^T : 8 h-tiles x 1 MFMA (K=32 = whole chunk)
    bf16x8 pf = *(bf16x8*)&myP[ln * 36 + quad * 8];
#pragma unroll
    for (int ht = 0; ht < 8; ++ht) {
      const int hrow = ht * 16 + ln;
      const int slot = quad ^ (hrow & 3) ^ ((hrow >> 2) & 3);
      bf16x8 vf = *(bf16x8*)&Vc[hrow * 32 + slot * 8];
      oacc[ht] = __builtin_amdgcn_mfma_f32_16x16x32_bf16(vf, pf, oacc[ht], 0, 0, 0);
    }
  }

  // write partial: m, l per query; un-normalized O via LDS transpose
  if (quad == 0) {
    pm[(size_t)sid * 64 + wv * 16 + ln] = m_run;
    pl[(size_t)sid * 64 + wv * 16 + ln] = l_run;
  }
  __syncthreads();  // Ks/Vt/Pt dead; reuse for Ot
  float* Ot = (float*)smem;  // [64][132] f32 = 33.8 KB (fits in 37.4 KB)
#pragma unroll
  for (int ht = 0; ht < 8; ++ht)
    *(f32x4*)&Ot[(wv * 16 + ln) * 132 + ht * 16 + quad * 4] = oacc[ht];
  __syncthreads();
  float* dst = po + (size_t)sid * 8192;
#pragma unroll
  for (int i = 0; i < 8; ++i) {
    int slot2 = tid + i * 256;            // 2048 float4 slots: 64 q x 32
    int r2 = slot2 >> 5, c2 = slot2 & 31;
    *(f32x4*)(dst + r2 * 128 + c2 * 4) = *(f32x4*)&Ot[r2 * 132 + c2 * 4];
  }
}

// ---------------------------------------------------------------------------
// Attention part 2: combine <=4 partials per (b, 64q-tile) with max-rescale.
// 256 blocks x 256 thr; thread -> (q = tid>>2, 32 h-dims).
// ---------------------------------------------------------------------------
__global__ __launch_bounds__(256) void attn_reduce(
    const float* __restrict__ po, const float* __restrict__ pm,
    const float* __restrict__ pl, float* __restrict__ out) {
  const int b = blockIdx.x >> 5;
  const int j = blockIdx.x & 31;
  const int g = j >> 3;
  const int nseg = g + 1;
  const int sid0 = b * 80 + 4 * g * (g + 1) + (j - 8 * g) * nseg;
  const int tid = threadIdx.x;
  const int q = tid >> 2, hq = tid & 3;

  float m[4], l[4], a[4];
  float M = -INFINITY;
  for (int s2 = 0; s2 < nseg; ++s2) {
    m[s2] = pm[(size_t)(sid0 + s2) * 64 + q];
    l[s2] = pl[(size_t)(sid0 + s2) * 64 + q];
    M = fmaxf(M, m[s2]);
  }
  float lsum = 0.f;
  for (int s2 = 0; s2 < nseg; ++s2) {
    a[s2] = __expf(m[s2] - M);
    lsum += a[s2] * l[s2];
  }
  f32x4 acc[8];
#pragma unroll
  for (int i = 0; i < 8; ++i) acc[i] = (f32x4){0.f, 0.f, 0.f, 0.f};
  for (int s2 = 0; s2 < nseg; ++s2) {
    const float* src = po + (size_t)(sid0 + s2) * 8192 + q * 128 + hq * 32;
    const float as = a[s2];
#pragma unroll
    for (int i = 0; i < 8; ++i) {
      f32x4 v = *(const f32x4*)(src + i * 4);
#pragma unroll
      for (int c = 0; c < 4; ++c) acc[i][c] += as * v[c];
    }
  }
  const float inv = 1.0f / lsum;
  float* o = out + ((size_t)(b * T_ + j * 64 + q)) * H_ + hq * 32;
#pragma unroll
  for (int i = 0; i < 8; ++i) {
    f32x4 v;
#pragma unroll
    for (int c = 0; c < 4; ++c) v[c] = acc[i][c] * inv;
    *(f32x4*)(o + i * 4) = v;
  }
}

// ---------------------------------------------------------------------------
extern "C" void kernel_launch(void* const* d_in, const int* in_sizes, int n_in,
                              void* d_out, int out_size, void* d_ws, size_t ws_size,
                              hipStream_t stream) {
  const float* x  = (const float*)d_in[0];
  const float* Wq = (const float*)d_in[1];
  const float* Wk = (const float*)d_in[2];
  const float* Wv = (const float*)d_in[3];
  float* out = (float*)d_out;

  char* ws = (char*)d_ws;
  short* qb  = (short*)(ws);                // 4 MB   q  bf16 [BT][128]
  short* kb  = (short*)(ws + 4194304);      // 4 MB   k  bf16 [BT][128]
  short* vtb = (short*)(ws + 8388608);      // 4 MB   v^T bf16 [B][128][T]
  short* Wt  = (short*)(ws + 12582912);     // 0.75 MB W^T bf16 [3][128][1024]
  float* po  = (float*)(ws + 14680064);     // 20 MB  partial O (640 x 32 KB)
  float* pm  = (float*)(ws + 35651584);     // 160 KB partial m
  float* pl  = (float*)(ws + 35915776);     // 160 KB partial l

  wcvt_kernel<<<dim3(D_ / 64, 3), 256, 0, stream>>>(Wq, Wk, Wv, Wt);
  proj_kernel<<<dim3(BT / 64), 256, 0, stream>>>(x, Wt, qb, kb, vtb);
  attn_part<<<dim3(8 * 80), 256, 0, stream>>>(qb, kb, vtb, po, pm, pl);
  attn_reduce<<<dim3(8 * 32), 256, 0, stream>>>(po, pm, pl, out);
}

// Round 8
// 157.259 us; speedup vs baseline: 1.0514x; 1.0514x over previous
//
#include <hip/hip_runtime.h>
#include <math.h>

#define B_ 8
#define T_ 2048
#define D_ 1024
#define H_ 128
#define BT (B_ * T_)

typedef short bf16x8 __attribute__((ext_vector_type(8)));
typedef float f32x4 __attribute__((ext_vector_type(4)));

static constexpr float SCALE = 0.08838834764831845f;  // 1/sqrt(128)

__device__ inline unsigned short f2b(float f) {
  unsigned int u = __float_as_uint(f);
  u += 0x7FFF + ((u >> 16) & 1);  // RNE
  return (unsigned short)(u >> 16);
}
__device__ inline unsigned int pk2(float a, float b) {
  return (unsigned int)f2b(a) | ((unsigned int)f2b(b) << 16);
}
// single-instruction RNE pack (gfx950 v_cvt_pk_bf16_f32): lo=a, hi=b
__device__ __forceinline__ unsigned int pk2f(float a, float b) {
  unsigned int r;
  asm("v_cvt_pk_bf16_f32 %0, %1, %2" : "=v"(r) : "v"(a), "v"(b));
  return r;
}

// global (AS1) -> LDS (AS3) direct 16B copy; dest = wave-uniform base + lane*16
__device__ __forceinline__ void gll16(const void* g, void* l) {
  __builtin_amdgcn_global_load_lds(
      (const __attribute__((address_space(1))) void*)g,
      (__attribute__((address_space(3))) void*)l, 16, 0, 0);
}

// ---------------------------------------------------------------------------
// Setup: W[d][h] fp32 -> Wt[sel][h][d] bf16 through LDS, coalesced stores.
// ---------------------------------------------------------------------------
__global__ __launch_bounds__(256) void wcvt_kernel(
    const float* __restrict__ Wq, const float* __restrict__ Wk,
    const float* __restrict__ Wv, short* __restrict__ Wt) {
  __shared__ short Wls[128 * 72];  // [h][d] bf16, pitch 72
  const int sel = blockIdx.y;
  const float* W = sel == 0 ? Wq : (sel == 1 ? Wk : Wv);
  const int d0 = blockIdx.x * 64;
  const int tid = threadIdx.x;
#pragma unroll
  for (int i = 0; i < 8; ++i) {
    int slot = tid + i * 256;         // 2048 float4 slots: 64 d x 32 h-groups
    int r = slot >> 5, hg = slot & 31;
    float4 w = *(const float4*)(W + (size_t)(d0 + r) * H_ + hg * 4);
    Wls[(hg * 4 + 0) * 72 + r] = (short)f2b(w.x);
    Wls[(hg * 4 + 1) * 72 + r] = (short)f2b(w.y);
    Wls[(hg * 4 + 2) * 72 + r] = (short)f2b(w.z);
    Wls[(hg * 4 + 3) * 72 + r] = (short)f2b(w.w);
  }
  __syncthreads();
  short* dst = Wt + (size_t)sel * D_ * H_;
#pragma unroll
  for (int i = 0; i < 4; ++i) {
    int slot = tid + i * 256;         // 1024 int4 slots: 128 h x 8 d-groups
    int h = slot >> 3, g = slot & 7;
    *(int4*)(dst + (size_t)h * D_ + d0 + g * 8) = *(int4*)&Wls[h * 72 + g * 8];
  }
}

// ---------------------------------------------------------------------------
// Proj (v3, resubmitted — round-7 run died in container infra, not the
// kernel): round-5 split structure (round-6 fusion proved x's 3x re-read is
// L3-absorbed; fusion only cost occupancy, 44 vs 28 µs). One change vs
// round 5: X-staging repack uses v_cvt_pk_bf16_f32 (1 inst per 2 values)
// instead of manual bit-RNE (~10 VALU per 2 values).
// ---------------------------------------------------------------------------
__global__ __launch_bounds__(256) void proj_kernel(
    const float* __restrict__ x, const short* __restrict__ Wt,
    short* __restrict__ qb, short* __restrict__ kb, short* __restrict__ vtb) {
  __shared__ alignas(16) char smem[49152];
  short* Xs0 = (short*)smem;             // [64][64] bf16 swizzled
  short* Xs1 = (short*)(smem + 8192);
  short* Ws0 = (short*)(smem + 16384);   // [128][64] bf16 swizzled
  short* Ws1 = (short*)(smem + 32768);

  const int tid = threadIdx.x;
  const int wave = tid >> 6, lane = tid & 63;
  const int ln = lane & 15, quad = lane >> 4;
  const int mw = wave & 1, nw = wave >> 1;  // wave tile: 32 rows x 64 cols
  const int sel = blockIdx.y;
  const int row0 = blockIdx.x * 64;
  const short* W = Wt + (size_t)sel * (size_t)(D_ * H_);

  f32x4 acc[2][4];
#pragma unroll
  for (int mi = 0; mi < 2; ++mi)
#pragma unroll
    for (int ni = 0; ni < 4; ++ni) acc[mi][ni] = (f32x4){0.f, 0.f, 0.f, 0.f};

  auto stage = [&](int bf, int k0) {
    short* Ws = bf ? Ws1 : Ws0;
#pragma unroll
    for (int j = 0; j < 4; ++j) {
      const int rbase = wave * 32 + j * 8;
      const int n = rbase + (lane >> 3);
      const int gp = (lane & 7) ^ (n & 7);
      gll16(W + (size_t)n * D_ + k0 + gp * 8, (char*)Ws + rbase * 128);
    }
    short* Xs = bf ? Xs1 : Xs0;
    float4 xr[4];
#pragma unroll
    for (int i = 0; i < 4; ++i) {
      int fid = tid + i * 256;           // 1024 float4 slots: 64 rows x 16
      int r = fid >> 4, g4 = fid & 15;
      xr[i] = *(const float4*)(x + (size_t)(row0 + r) * D_ + k0 + g4 * 4);
    }
#pragma unroll
    for (int i = 0; i < 4; ++i) {
      int fid = tid + i * 256;
      int r = fid >> 4, g4 = fid & 15;
      int g = g4 >> 1, half = g4 & 1;
      unsigned int* p = (unsigned int*)&Xs[r * 64 + ((g ^ (r & 7)) * 8) + half * 4];
      p[0] = pk2f(xr[i].x, xr[i].y);
      p[1] = pk2f(xr[i].z, xr[i].w);
    }
  };

  stage(0, 0);  // prologue
  for (int s = 0; s < 16; ++s) {
    __syncthreads();  // drains buf[s&1] (gll + ds_write); prev compute done
    if (s < 15) stage((s + 1) & 1, (s + 1) * 64);
    const short* Xs = (s & 1) ? Xs1 : Xs0;
    const short* Ws = (s & 1) ? Ws1 : Ws0;
#pragma unroll
    for (int kk = 0; kk < 2; ++kk) {
      bf16x8 a[2];
#pragma unroll
      for (int mi = 0; mi < 2; ++mi) {
        int r = mw * 32 + mi * 16 + ln;
        a[mi] = *(bf16x8*)&Xs[r * 64 + (((kk * 4 + quad) ^ (r & 7)) * 8)];
      }
#pragma unroll
      for (int ni = 0; ni < 4; ++ni) {
        int n = nw * 64 + ni * 16 + ln;
        bf16x8 bb = *(bf16x8*)&Ws[n * 64 + (((kk * 4 + quad) ^ (n & 7)) * 8)];
#pragma unroll
        for (int mi = 0; mi < 2; ++mi)
          acc[mi][ni] = __builtin_amdgcn_mfma_f32_16x16x32_bf16(a[mi], bb, acc[mi][ni], 0, 0, 0);
      }
    }
  }

  __syncthreads();  // tiles dead; reuse smem for epilogue repack
  short* Cs = (short*)smem;
  if (sel < 2) {
    short* out = sel ? kb : qb;
#pragma unroll
    for (int mi = 0; mi < 2; ++mi)
#pragma unroll
      for (int ni = 0; ni < 4; ++ni)
#pragma unroll
        for (int rr = 0; rr < 4; ++rr)
          Cs[(mw * 32 + mi * 16 + quad * 4 + rr) * 136 + nw * 64 + ni * 16 + ln] =
              (short)f2b(acc[mi][ni][rr]);
    __syncthreads();
#pragma unroll
    for (int i = 0; i < 4; ++i) {
      int slot = tid + i * 256;          // 1024 int4 slots: 64 rows x 16
      int r = slot >> 4, g = slot & 15;
      *(int4*)(out + (size_t)(row0 + r) * H_ + g * 8) = *(int4*)&Cs[r * 136 + g * 8];
    }
  } else {
#pragma unroll
    for (int mi = 0; mi < 2; ++mi)
#pragma unroll
      for (int ni = 0; ni < 4; ++ni)
#pragma unroll
        for (int rr = 0; rr < 4; ++rr)
          Cs[(nw * 64 + ni * 16 + ln) * 72 + mw * 32 + mi * 16 + quad * 4 + rr] =
              (short)f2b(acc[mi][ni][rr]);
    __syncthreads();
    const int b = row0 >> 11, t0 = row0 & 2047;
#pragma unroll
    for (int i = 0; i < 4; ++i) {
      int slot = tid + i * 256;          // 1024 int4 slots: 128 h x 8
      int h = slot >> 3, g = slot & 7;
      *(int4*)(vtb + (size_t)(b * H_ + h) * T_ + t0 + g * 8) = *(int4*)&Cs[h * 72 + g * 8];
    }
  }
}

// ---------------------------------------------------------------------------
// Attention part 1 (v5, unchanged): 32-key chunks, K+V LDS dbuf via gll,
// one barrier per chunk, 4 blocks/CU, defer-max, XCD affinity.
// ---------------------------------------------------------------------------
__global__ __launch_bounds__(256, 4) void attn_part(
    const short* __restrict__ qb, const short* __restrict__ kb,
    const short* __restrict__ vtb, float* __restrict__ po,
    float* __restrict__ pm, float* __restrict__ pl) {
  __shared__ alignas(16) char smem[37376];
  short* Ks0 = (short*)smem;               // [32][128] bf16 swizzled, 8 KB
  short* Ks1 = (short*)(smem + 8192);
  short* Vt0 = (short*)(smem + 16384);     // [128][32] bf16 swizzled, 8 KB
  short* Vt1 = (short*)(smem + 24576);
  short* Pt  = (short*)(smem + 32768);     // 4 waves x [16][36] bf16, 4.5 KB

  const int tid = threadIdx.x;
  const int wv = tid >> 6, lane = tid & 63;
  const int ln = lane & 15, quad = lane >> 4;
  const int b = blockIdx.x & 7;            // XCD-affinity: xcd = id % 8 = b
  const int rr = 79 - (blockIdx.x >> 3);   // heavy segments first
  // decode rr -> (j, s):  group g = j>>3 has nseg g+1; cum base 4g(g+1)
  const int g = (rr >= 48) ? 3 : (rr >= 24) ? 2 : (rr >= 8) ? 1 : 0;
  const int local = rr - 4 * g * (g + 1);
  const int j = 8 * g + local / (g + 1);
  const int s = local - (local / (g + 1)) * (g + 1);
  const int sid = b * 80 + rr;             // partial storage slot
  const int q0 = j * 64;
  const int nchunks = min(16, 2 * (j + 1) - 16 * s);  // 32-key chunks

  short* myP = Pt + wv * (16 * 36);
  const int qglob = q0 + wv * 16 + ln;

  bf16x8 qfr[4];  // this wave's 16 queries, B-operand layout
#pragma unroll
  for (int kk = 0; kk < 4; ++kk)
    qfr[kk] = *(const bf16x8*)(qb + (size_t)(b * T_ + q0 + wv * 16 + ln) * H_ +
                               kk * 32 + quad * 8);

  f32x4 oacc[8];  // O^T: h = ht*16+quad*4+r, q = ln
#pragma unroll
  for (int ht = 0; ht < 8; ++ht) oacc[ht] = (f32x4){0.f, 0.f, 0.f, 0.f};

  float m_run = -INFINITY, l_run = 0.f;

  auto stageK = [&](short* dst, int s0) {
#pragma unroll
    for (int jj = 0; jj < 2; ++jj) {
      const int rb = wv * 8 + jj * 4;        // 8 rows per wave (32 total)
      const int r = rb + (lane >> 4);
      const int gp = (lane & 15) ^ (r & 7);
      gll16(kb + (size_t)(b * T_ + s0 + r) * H_ + gp * 8, (char*)dst + rb * 256);
    }
  };
  auto stageV = [&](short* dst, int s0) {
#pragma unroll
    for (int jj = 0; jj < 2; ++jj) {
      const int hb = wv * 32 + jj * 16;      // 32 rows per wave (128 total)
      const int h = hb + (lane >> 2);
      const int gp = (lane & 3) ^ (h & 3) ^ ((h >> 2) & 3);
      gll16(vtb + (size_t)(b * H_ + h) * T_ + s0 + gp * 8, (char*)dst + hb * 64);
    }
  };

  stageK(Ks0, 512 * s);  // prologue: first 32-key chunk of this segment
  stageV(Vt0, 512 * s);

  for (int ch = 0; ch < nchunks; ++ch) {
    const int s0 = 512 * s + ch * 32;
    const int cur = ch & 1;
    __syncthreads();  // drains gll for buf[cur]; other buffer free to restage
    if (ch + 1 < nchunks) {
      stageK(cur ? Ks0 : Ks1, s0 + 32);
      stageV(cur ? Vt0 : Vt1, s0 + 32);
    }
    const short* Kc = cur ? Ks1 : Ks0;
    const short* Vc = cur ? Vt1 : Vt0;

    // S^T = K * Q^T : 2 key-tiles x 4 kk = 8 MFMAs (per wave, its 16 q)
    f32x4 sacc[2];
#pragma unroll
    for (int t = 0; t < 2; ++t) sacc[t] = (f32x4){0.f, 0.f, 0.f, 0.f};
#pragma unroll
    for (int kk = 0; kk < 4; ++kk) {
#pragma unroll
      for (int t = 0; t < 2; ++t) {
        const int krow = t * 16 + ln;
        bf16x8 kf = *(bf16x8*)&Kc[krow * 128 + (((kk * 4 + quad) ^ (krow & 7)) * 8)];
        sacc[t] = __builtin_amdgcn_mfma_f32_16x16x32_bf16(kf, qfr[kk], sacc[t], 0, 0, 0);
      }
    }

    // wave-local online softmax over 32 keys
    float sv[2][4];
    float mc = -INFINITY;
    if (s0 + 31 <= q0 + wv * 16) {  // chunk fully visible for this wave
#pragma unroll
      for (int t = 0; t < 2; ++t)
#pragma unroll
        for (int r = 0; r < 4; ++r) {
          sv[t][r] = sacc[t][r] * SCALE;
          mc = fmaxf(mc, sv[t][r]);
        }
    } else {
#pragma unroll
      for (int t = 0; t < 2; ++t)
#pragma unroll
        for (int r = 0; r < 4; ++r) {
          const int key = s0 + t * 16 + quad * 4 + r;
          float sc = sacc[t][r] * SCALE;
          sv[t][r] = (key <= qglob) ? sc : -INFINITY;
          mc = fmaxf(mc, sv[t][r]);
        }
    }
    mc = fmaxf(mc, __shfl_xor(mc, 16));
    mc = fmaxf(mc, __shfl_xor(mc, 32));

    // defer-max (T13): skip the O-rescale unless the max grew by > 8.
    // (-inf chunks: mc=-inf <= m_run+8 even at m_run=-inf -> skip, p=0.)
    if (!__all(mc <= m_run + 8.f)) {
      const float mnew = fmaxf(m_run, mc);
      const float alpha = __expf(m_run - mnew);
#pragma unroll
      for (int ht = 0; ht < 8; ++ht)
#pragma unroll
        for (int r = 0; r < 4; ++r) oacc[ht][r] *= alpha;
      l_run *= alpha;
      m_run = mnew;
    }
    float lc = 0.f;
    float p[2][4];
#pragma unroll
    for (int t = 0; t < 2; ++t)
#pragma unroll
      for (int r = 0; r < 4; ++r) {
        p[t][r] = __expf(sv[t][r] - m_run);
        lc += p[t][r];
      }
    lc += __shfl_xor(lc, 16);
    lc += __shfl_xor(lc, 32);
    l_run += lc;

    // P^T -> wave-private LDS scratch (same-wave lgkm-ordered; no barrier)
#pragma unroll
    for (int t = 0; t < 2; ++t) {
      *(unsigned int*)&myP[ln * 36 + t * 16 + quad * 4 + 0] = pk2(p[t][0], p[t][1]);
      *(unsigned int*)&myP[ln * 36 + t * 16 + quad * 4 + 2] = pk2(p[t][2], p[t][3]);
    }

    // O^T += V^T * P^T : 8 h-tiles x 1 MFMA (K=32 = whole chunk)
    bf16x8 pf = *(bf16x8*)&myP[ln * 36 + quad * 8];
#pragma unroll
    for (int ht = 0; ht < 8; ++ht) {
      const int hrow = ht * 16 + ln;
      const int slot = quad ^ (hrow & 3) ^ ((hrow >> 2) & 3);
      bf16x8 vf = *(bf16x8*)&Vc[hrow * 32 + slot * 8];
      oacc[ht] = __builtin_amdgcn_mfma_f32_16x16x32_bf16(vf, pf, oacc[ht], 0, 0, 0);
    }
  }

  // write partial: m, l per query; un-normalized O via LDS transpose
  if (quad == 0) {
    pm[(size_t)sid * 64 + wv * 16 + ln] = m_run;
    pl[(size_t)sid * 64 + wv * 16 + ln] = l_run;
  }
  __syncthreads();  // Ks/Vt/Pt dead; reuse for Ot
  float* Ot = (float*)smem;  // [64][132] f32 = 33.8 KB (fits in 37.4 KB)
#pragma unroll
  for (int ht = 0; ht < 8; ++ht)
    *(f32x4*)&Ot[(wv * 16 + ln) * 132 + ht * 16 + quad * 4] = oacc[ht];
  __syncthreads();
  float* dst = po + (size_t)sid * 8192;
#pragma unroll
  for (int i = 0; i < 8; ++i) {
    int slot2 = tid + i * 256;            // 2048 float4 slots: 64 q x 32
    int r2 = slot2 >> 5, c2 = slot2 & 31;
    *(f32x4*)(dst + r2 * 128 + c2 * 4) = *(f32x4*)&Ot[r2 * 132 + c2 * 4];
  }
}

// ---------------------------------------------------------------------------
// Attention part 2: combine <=4 partials per (b, 64q-tile) with max-rescale.
// 256 blocks x 256 thr; thread -> (q = tid>>2, 32 h-dims).
// ---------------------------------------------------------------------------
__global__ __launch_bounds__(256) void attn_reduce(
    const float* __restrict__ po, const float* __restrict__ pm,
    const float* __restrict__ pl, float* __restrict__ out) {
  const int b = blockIdx.x >> 5;
  const int j = blockIdx.x & 31;
  const int g = j >> 3;
  const int nseg = g + 1;
  const int sid0 = b * 80 + 4 * g * (g + 1) + (j - 8 * g) * nseg;
  const int tid = threadIdx.x;
  const int q = tid >> 2, hq = tid & 3;

  float m[4], l[4], a[4];
  float M = -INFINITY;
  for (int s2 = 0; s2 < nseg; ++s2) {
    m[s2] = pm[(size_t)(sid0 + s2) * 64 + q];
    l[s2] = pl[(size_t)(sid0 + s2) * 64 + q];
    M = fmaxf(M, m[s2]);
  }
  float lsum = 0.f;
  for (int s2 = 0; s2 < nseg; ++s2) {
    a[s2] = __expf(m[s2] - M);
    lsum += a[s2] * l[s2];
  }
  f32x4 acc[8];
#pragma unroll
  for (int i = 0; i < 8; ++i) acc[i] = (f32x4){0.f, 0.f, 0.f, 0.f};
  for (int s2 = 0; s2 < nseg; ++s2) {
    const float* src = po + (size_t)(sid0 + s2) * 8192 + q * 128 + hq * 32;
    const float as = a[s2];
#pragma unroll
    for (int i = 0; i < 8; ++i) {
      f32x4 v = *(const f32x4*)(src + i * 4);
#pragma unroll
      for (int c = 0; c < 4; ++c) acc[i][c] += as * v[c];
    }
  }
  const float inv = 1.0f / lsum;
  float* o = out + ((size_t)(b * T_ + j * 64 + q)) * H_ + hq * 32;
#pragma unroll
  for (int i = 0; i < 8; ++i) {
    f32x4 v;
#pragma unroll
    for (int c = 0; c < 4; ++c) v[c] = acc[i][c] * inv;
    *(f32x4*)(o + i * 4) = v;
  }
}

// ---------------------------------------------------------------------------
extern "C" void kernel_launch(void* const* d_in, const int* in_sizes, int n_in,
                              void* d_out, int out_size, void* d_ws, size_t ws_size,
                              hipStream_t stream) {
  const float* x  = (const float*)d_in[0];
  const float* Wq = (const float*)d_in[1];
  const float* Wk = (const float*)d_in[2];
  const float* Wv = (const float*)d_in[3];
  float* out = (float*)d_out;

  char* ws = (char*)d_ws;
  short* qb  = (short*)(ws);                // 4 MB   q  bf16 [BT][128]
  short* kb  = (short*)(ws + 4194304);      // 4 MB   k  bf16 [BT][128]
  short* vtb = (short*)(ws + 8388608);      // 4 MB   v^T bf16 [B][128][T]
  short* Wt  = (short*)(ws + 12582912);     // 0.75 MB W^T bf16 [3][128][1024]
  float* po  = (float*)(ws + 14680064);     // 20 MB  partial O (640 x 32 KB)
  float* pm  = (float*)(ws + 35651584);     // 160 KB partial m
  float* pl  = (float*)(ws + 35915776);     // 160 KB partial l

  wcvt_kernel<<<dim3(D_ / 64, 3), 256, 0, stream>>>(Wq, Wk, Wv, Wt);
  proj_kernel<<<dim3(BT / 64, 3), 256, 0, stream>>>(x, Wt, qb, kb, vtb);
  attn_part<<<dim3(8 * 80), 256, 0, stream>>>(qb, kb, vtb, po, pm, pl);
  attn_reduce<<<dim3(8 * 32), 256, 0, stream>>>(po, pm, pl, out);
}

// Round 9
// 154.319 us; speedup vs baseline: 1.0714x; 1.0190x over previous
//
#include <hip/hip_runtime.h>
#include <math.h>

#define B_ 8
#define T_ 2048
#define D_ 1024
#define H_ 128
#define BT (B_ * T_)

typedef short bf16x8 __attribute__((ext_vector_type(8)));
typedef short bf16x4 __attribute__((ext_vector_type(4)));
typedef float f32x4 __attribute__((ext_vector_type(4)));
typedef int i32x2 __attribute__((ext_vector_type(2)));

static constexpr float SCALE = 0.08838834764831845f;  // 1/sqrt(128)

__device__ inline unsigned short f2b(float f) {
  unsigned int u = __float_as_uint(f);
  u += 0x7FFF + ((u >> 16) & 1);  // RNE
  return (unsigned short)(u >> 16);
}
__device__ inline unsigned int pk2(float a, float b) {
  return (unsigned int)f2b(a) | ((unsigned int)f2b(b) << 16);
}
// single-instruction RNE pack (gfx950 v_cvt_pk_bf16_f32): lo=a, hi=b
__device__ __forceinline__ unsigned int pk2f(float a, float b) {
  unsigned int r;
  asm("v_cvt_pk_bf16_f32 %0, %1, %2" : "=v"(r) : "v"(a), "v"(b));
  return r;
}
// K=16 bf16 MFMA (ISA-listed on gfx950): D=C tied, A/B are 4 bf16 (2 VGPRs)
__device__ __forceinline__ void mfma16(f32x4& d, bf16x4 a, bf16x4 b) {
  asm("v_mfma_f32_16x16x16_bf16 %0, %1, %2, %0" : "+v"(d) : "v"(a), "v"(b));
}

// global (AS1) -> LDS (AS3) direct 16B copy; dest = wave-uniform base + lane*16
__device__ __forceinline__ void gll16(const void* g, void* l) {
  __builtin_amdgcn_global_load_lds(
      (const __attribute__((address_space(1))) void*)g,
      (__attribute__((address_space(3))) void*)l, 16, 0, 0);
}

// ---------------------------------------------------------------------------
// Setup: W[d][h] fp32 -> Wt[sel][h][d] bf16 through LDS, coalesced stores.
// ---------------------------------------------------------------------------
__global__ __launch_bounds__(256) void wcvt_kernel(
    const float* __restrict__ Wq, const float* __restrict__ Wk,
    const float* __restrict__ Wv, short* __restrict__ Wt) {
  __shared__ short Wls[128 * 72];  // [h][d] bf16, pitch 72
  const int sel = blockIdx.y;
  const float* W = sel == 0 ? Wq : (sel == 1 ? Wk : Wv);
  const int d0 = blockIdx.x * 64;
  const int tid = threadIdx.x;
#pragma unroll
  for (int i = 0; i < 8; ++i) {
    int slot = tid + i * 256;         // 2048 float4 slots: 64 d x 32 h-groups
    int r = slot >> 5, hg = slot & 31;
    float4 w = *(const float4*)(W + (size_t)(d0 + r) * H_ + hg * 4);
    Wls[(hg * 4 + 0) * 72 + r] = (short)f2b(w.x);
    Wls[(hg * 4 + 1) * 72 + r] = (short)f2b(w.y);
    Wls[(hg * 4 + 2) * 72 + r] = (short)f2b(w.z);
    Wls[(hg * 4 + 3) * 72 + r] = (short)f2b(w.w);
  }
  __syncthreads();
  short* dst = Wt + (size_t)sel * D_ * H_;
#pragma unroll
  for (int i = 0; i < 4; ++i) {
    int slot = tid + i * 256;         // 1024 int4 slots: 128 h x 8 d-groups
    int h = slot >> 3, g = slot & 7;
    *(int4*)(dst + (size_t)h * D_ + d0 + g * 8) = *(int4*)&Wls[h * 72 + g * 8];
  }
}

// ---------------------------------------------------------------------------
// Proj (v3, unchanged from round 8): split (256,3) grid, gll dbuf, cvt_pk
// staging pack.
// ---------------------------------------------------------------------------
__global__ __launch_bounds__(256) void proj_kernel(
    const float* __restrict__ x, const short* __restrict__ Wt,
    short* __restrict__ qb, short* __restrict__ kb, short* __restrict__ vtb) {
  __shared__ alignas(16) char smem[49152];
  short* Xs0 = (short*)smem;             // [64][64] bf16 swizzled
  short* Xs1 = (short*)(smem + 8192);
  short* Ws0 = (short*)(smem + 16384);   // [128][64] bf16 swizzled
  short* Ws1 = (short*)(smem + 32768);

  const int tid = threadIdx.x;
  const int wave = tid >> 6, lane = tid & 63;
  const int ln = lane & 15, quad = lane >> 4;
  const int mw = wave & 1, nw = wave >> 1;  // wave tile: 32 rows x 64 cols
  const int sel = blockIdx.y;
  const int row0 = blockIdx.x * 64;
  const short* W = Wt + (size_t)sel * (size_t)(D_ * H_);

  f32x4 acc[2][4];
#pragma unroll
  for (int mi = 0; mi < 2; ++mi)
#pragma unroll
    for (int ni = 0; ni < 4; ++ni) acc[mi][ni] = (f32x4){0.f, 0.f, 0.f, 0.f};

  auto stage = [&](int bf, int k0) {
    short* Ws = bf ? Ws1 : Ws0;
#pragma unroll
    for (int j = 0; j < 4; ++j) {
      const int rbase = wave * 32 + j * 8;
      const int n = rbase + (lane >> 3);
      const int gp = (lane & 7) ^ (n & 7);
      gll16(W + (size_t)n * D_ + k0 + gp * 8, (char*)Ws + rbase * 128);
    }
    short* Xs = bf ? Xs1 : Xs0;
    float4 xr[4];
#pragma unroll
    for (int i = 0; i < 4; ++i) {
      int fid = tid + i * 256;           // 1024 float4 slots: 64 rows x 16
      int r = fid >> 4, g4 = fid & 15;
      xr[i] = *(const float4*)(x + (size_t)(row0 + r) * D_ + k0 + g4 * 4);
    }
#pragma unroll
    for (int i = 0; i < 4; ++i) {
      int fid = tid + i * 256;
      int r = fid >> 4, g4 = fid & 15;
      int g = g4 >> 1, half = g4 & 1;
      unsigned int* p = (unsigned int*)&Xs[r * 64 + ((g ^ (r & 7)) * 8) + half * 4];
      p[0] = pk2f(xr[i].x, xr[i].y);
      p[1] = pk2f(xr[i].z, xr[i].w);
    }
  };

  stage(0, 0);  // prologue
  for (int s = 0; s < 16; ++s) {
    __syncthreads();  // drains buf[s&1] (gll + ds_write); prev compute done
    if (s < 15) stage((s + 1) & 1, (s + 1) * 64);
    const short* Xs = (s & 1) ? Xs1 : Xs0;
    const short* Ws = (s & 1) ? Ws1 : Ws0;
#pragma unroll
    for (int kk = 0; kk < 2; ++kk) {
      bf16x8 a[2];
#pragma unroll
      for (int mi = 0; mi < 2; ++mi) {
        int r = mw * 32 + mi * 16 + ln;
        a[mi] = *(bf16x8*)&Xs[r * 64 + (((kk * 4 + quad) ^ (r & 7)) * 8)];
      }
#pragma unroll
      for (int ni = 0; ni < 4; ++ni) {
        int n = nw * 64 + ni * 16 + ln;
        bf16x8 bb = *(bf16x8*)&Ws[n * 64 + (((kk * 4 + quad) ^ (n & 7)) * 8)];
#pragma unroll
        for (int mi = 0; mi < 2; ++mi)
          acc[mi][ni] = __builtin_amdgcn_mfma_f32_16x16x32_bf16(a[mi], bb, acc[mi][ni], 0, 0, 0);
      }
    }
  }

  __syncthreads();  // tiles dead; reuse smem for epilogue repack
  short* Cs = (short*)smem;
  if (sel < 2) {
    short* out = sel ? kb : qb;
#pragma unroll
    for (int mi = 0; mi < 2; ++mi)
#pragma unroll
      for (int ni = 0; ni < 4; ++ni)
#pragma unroll
        for (int rr = 0; rr < 4; ++rr)
          Cs[(mw * 32 + mi * 16 + quad * 4 + rr) * 136 + nw * 64 + ni * 16 + ln] =
              (short)f2b(acc[mi][ni][rr]);
    __syncthreads();
#pragma unroll
    for (int i = 0; i < 4; ++i) {
      int slot = tid + i * 256;          // 1024 int4 slots: 64 rows x 16
      int r = slot >> 4, g = slot & 15;
      *(int4*)(out + (size_t)(row0 + r) * H_ + g * 8) = *(int4*)&Cs[r * 136 + g * 8];
    }
  } else {
#pragma unroll
    for (int mi = 0; mi < 2; ++mi)
#pragma unroll
      for (int ni = 0; ni < 4; ++ni)
#pragma unroll
        for (int rr = 0; rr < 4; ++rr)
          Cs[(nw * 64 + ni * 16 + ln) * 72 + mw * 32 + mi * 16 + quad * 4 + rr] =
              (short)f2b(acc[mi][ni][rr]);
    __syncthreads();
    const int b = row0 >> 11, t0 = row0 & 2047;
#pragma unroll
    for (int i = 0; i < 4; ++i) {
      int slot = tid + i * 256;          // 1024 int4 slots: 128 h x 8
      int h = slot >> 3, g = slot & 7;
      *(int4*)(vtb + (size_t)(b * H_ + h) * T_ + t0 + g * 8) = *(int4*)&Cs[h * 72 + g * 8];
    }
  }
}

// ---------------------------------------------------------------------------
// Attention part 1 (v6): P stays in registers.
// Key insight: sacc's C-layout (col=q=ln, row=key=quad*4+r) IS the
// B-operand layout of v_mfma_f32_16x16x16_bf16 (k=quad*4+e, col=ln).
// PV = 2 x K=16 MFMAs per h-tile, P fed directly from softmax registers:
// no Pt LDS, no ds_write/ds_read, no lgkm sync on the softmax->PV path.
// LDS = K dbuf 16KB + V dbuf 16KB = 32768 B exactly -> 5 blocks/CU
// (160 KB/CU exactly), +25% latency-hiding chains vs round-5's 4.
// Epilogue Ot: granule-XOR-swizzled [64][128] f32 (32 KB, fits; ~2-way).
// ---------------------------------------------------------------------------
__global__ __launch_bounds__(256, 5) void attn_part(
    const short* __restrict__ qb, const short* __restrict__ kb,
    const short* __restrict__ vtb, float* __restrict__ po,
    float* __restrict__ pm, float* __restrict__ pl) {
  __shared__ alignas(16) char smem[32768];
  short* Ks0 = (short*)smem;               // [32][128] bf16 swizzled, 8 KB
  short* Ks1 = (short*)(smem + 8192);
  short* Vt0 = (short*)(smem + 16384);     // [128][32] bf16 swizzled, 8 KB
  short* Vt1 = (short*)(smem + 24576);

  const int tid = threadIdx.x;
  const int wv = tid >> 6, lane = tid & 63;
  const int ln = lane & 15, quad = lane >> 4;
  const int b = blockIdx.x & 7;            // XCD-affinity: xcd = id % 8 = b
  const int rr = 79 - (blockIdx.x >> 3);   // heavy segments first
  // decode rr -> (j, s):  group g = j>>3 has nseg g+1; cum base 4g(g+1)
  const int g = (rr >= 48) ? 3 : (rr >= 24) ? 2 : (rr >= 8) ? 1 : 0;
  const int local = rr - 4 * g * (g + 1);
  const int j = 8 * g + local / (g + 1);
  const int s = local - (local / (g + 1)) * (g + 1);
  const int sid = b * 80 + rr;             // partial storage slot
  const int q0 = j * 64;
  const int nchunks = min(16, 2 * (j + 1) - 16 * s);  // 32-key chunks

  const int qglob = q0 + wv * 16 + ln;

  bf16x8 qfr[4];  // this wave's 16 queries, B-operand layout
#pragma unroll
  for (int kk = 0; kk < 4; ++kk)
    qfr[kk] = *(const bf16x8*)(qb + (size_t)(b * T_ + q0 + wv * 16 + ln) * H_ +
                               kk * 32 + quad * 8);

  f32x4 oacc[8];  // O^T: h = ht*16+quad*4+r, q = ln
#pragma unroll
  for (int ht = 0; ht < 8; ++ht) oacc[ht] = (f32x4){0.f, 0.f, 0.f, 0.f};

  float m_run = -INFINITY, l_run = 0.f;

  auto stageK = [&](short* dst, int s0) {
#pragma unroll
    for (int jj = 0; jj < 2; ++jj) {
      const int rb = wv * 8 + jj * 4;        // 8 rows per wave (32 total)
      const int r = rb + (lane >> 4);
      const int gp = (lane & 15) ^ (r & 7);
      gll16(kb + (size_t)(b * T_ + s0 + r) * H_ + gp * 8, (char*)dst + rb * 256);
    }
  };
  auto stageV = [&](short* dst, int s0) {
#pragma unroll
    for (int jj = 0; jj < 2; ++jj) {
      const int hb = wv * 32 + jj * 16;      // 32 rows per wave (128 total)
      const int h = hb + (lane >> 2);
      const int gp = (lane & 3) ^ (h & 3) ^ ((h >> 2) & 3);
      gll16(vtb + (size_t)(b * H_ + h) * T_ + s0 + gp * 8, (char*)dst + hb * 64);
    }
  };

  stageK(Ks0, 512 * s);  // prologue: first 32-key chunk of this segment
  stageV(Vt0, 512 * s);

  for (int ch = 0; ch < nchunks; ++ch) {
    const int s0 = 512 * s + ch * 32;
    const int cur = ch & 1;
    __syncthreads();  // drains gll for buf[cur]; other buffer free to restage
    if (ch + 1 < nchunks) {
      stageK(cur ? Ks0 : Ks1, s0 + 32);
      stageV(cur ? Vt0 : Vt1, s0 + 32);
    }
    const short* Kc = cur ? Ks1 : Ks0;
    const short* Vc = cur ? Vt1 : Vt0;

    // S^T = K * Q^T : 2 key-tiles x 4 kk = 8 MFMAs (per wave, its 16 q)
    f32x4 sacc[2];
#pragma unroll
    for (int t = 0; t < 2; ++t) sacc[t] = (f32x4){0.f, 0.f, 0.f, 0.f};
#pragma unroll
    for (int kk = 0; kk < 4; ++kk) {
#pragma unroll
      for (int t = 0; t < 2; ++t) {
        const int krow = t * 16 + ln;
        bf16x8 kf = *(bf16x8*)&Kc[krow * 128 + (((kk * 4 + quad) ^ (krow & 7)) * 8)];
        sacc[t] = __builtin_amdgcn_mfma_f32_16x16x32_bf16(kf, qfr[kk], sacc[t], 0, 0, 0);
      }
    }

    // wave-local online softmax over 32 keys
    float sv[2][4];
    float mc = -INFINITY;
    if (s0 + 31 <= q0 + wv * 16) {  // chunk fully visible for this wave
#pragma unroll
      for (int t = 0; t < 2; ++t)
#pragma unroll
        for (int r = 0; r < 4; ++r) {
          sv[t][r] = sacc[t][r] * SCALE;
          mc = fmaxf(mc, sv[t][r]);
        }
    } else {
#pragma unroll
      for (int t = 0; t < 2; ++t)
#pragma unroll
        for (int r = 0; r < 4; ++r) {
          const int key = s0 + t * 16 + quad * 4 + r;
          float sc = sacc[t][r] * SCALE;
          sv[t][r] = (key <= qglob) ? sc : -INFINITY;
          mc = fmaxf(mc, sv[t][r]);
        }
    }
    mc = fmaxf(mc, __shfl_xor(mc, 16));
    mc = fmaxf(mc, __shfl_xor(mc, 32));

    // defer-max (T13): skip the O-rescale unless the max grew by > 8.
    // (-inf chunks: mc=-inf <= m_run+8 even at m_run=-inf -> skip, p=0.)
    if (!__all(mc <= m_run + 8.f)) {
      const float mnew = fmaxf(m_run, mc);
      const float alpha = __expf(m_run - mnew);
#pragma unroll
      for (int ht = 0; ht < 8; ++ht)
#pragma unroll
        for (int r = 0; r < 4; ++r) oacc[ht][r] *= alpha;
      l_run *= alpha;
      m_run = mnew;
    }
    float lc = 0.f;
    float p[2][4];
#pragma unroll
    for (int t = 0; t < 2; ++t)
#pragma unroll
      for (int r = 0; r < 4; ++r) {
        p[t][r] = __expf(sv[t][r] - m_run);
        lc += p[t][r];
      }
    lc += __shfl_xor(lc, 16);
    lc += __shfl_xor(lc, 32);
    l_run += lc;

    // O^T += V^T * P^T via 2 x K=16 MFMAs per h-tile: P direct from regs.
    // B-frag of 16x16x16 = (k=quad*4+e, col=ln) == sacc's C layout.
#pragma unroll
    for (int t = 0; t < 2; ++t) {
      i32x2 pp = {(int)pk2f(p[t][0], p[t][1]), (int)pk2f(p[t][2], p[t][3])};
      bf16x4 pf = __builtin_bit_cast(bf16x4, pp);
      const int gsl = t * 2 + (quad >> 1);   // k-granule (8 keys) index
      const int off = (quad & 1) * 4;        // 4-key sub-offset (shorts)
#pragma unroll
      for (int ht = 0; ht < 8; ++ht) {
        const int hrow = ht * 16 + ln;
        const int slot = gsl ^ ((hrow & 3) ^ ((hrow >> 2) & 3));
        bf16x4 vf = *(const bf16x4*)&Vc[hrow * 32 + slot * 8 + off];
        mfma16(oacc[ht], vf, pf);
      }
    }
  }

  // write partial: m, l per query; un-normalized O via swizzled LDS transpose
  if (quad == 0) {
    pm[(size_t)sid * 64 + wv * 16 + ln] = m_run;
    pl[(size_t)sid * 64 + wv * 16 + ln] = l_run;
  }
  __syncthreads();  // Ks/Vt dead; reuse for Ot
  float* Ot = (float*)smem;  // [64][128] f32, granule-XOR swizzled = 32 KB
#pragma unroll
  for (int ht = 0; ht < 8; ++ht) {
    const int row = wv * 16 + ln;
    const int cg = (ht * 4 + quad) ^ (row & 31);
    *(f32x4*)&Ot[row * 128 + cg * 4] = oacc[ht];
  }
  __syncthreads();
  float* dst = po + (size_t)sid * 8192;
#pragma unroll
  for (int i = 0; i < 8; ++i) {
    int slot2 = tid + i * 256;            // 2048 float4 slots: 64 q x 32
    int r2 = slot2 >> 5, c2 = slot2 & 31;
    *(f32x4*)(dst + r2 * 128 + c2 * 4) =
        *(f32x4*)&Ot[r2 * 128 + ((c2 ^ (r2 & 31)) * 4)];
  }
}

// ---------------------------------------------------------------------------
// Attention part 2: combine <=4 partials per (b, 64q-tile) with max-rescale.
// 256 blocks x 256 thr; thread -> (q = tid>>2, 32 h-dims).
// ---------------------------------------------------------------------------
__global__ __launch_bounds__(256) void attn_reduce(
    const float* __restrict__ po, const float* __restrict__ pm,
    const float* __restrict__ pl, float* __restrict__ out) {
  const int b = blockIdx.x >> 5;
  const int j = blockIdx.x & 31;
  const int g = j >> 3;
  const int nseg = g + 1;
  const int sid0 = b * 80 + 4 * g * (g + 1) + (j - 8 * g) * nseg;
  const int tid = threadIdx.x;
  const int q = tid >> 2, hq = tid & 3;

  float m[4], l[4], a[4];
  float M = -INFINITY;
  for (int s2 = 0; s2 < nseg; ++s2) {
    m[s2] = pm[(size_t)(sid0 + s2) * 64 + q];
    l[s2] = pl[(size_t)(sid0 + s2) * 64 + q];
    M = fmaxf(M, m[s2]);
  }
  float lsum = 0.f;
  for (int s2 = 0; s2 < nseg; ++s2) {
    a[s2] = __expf(m[s2] - M);
    lsum += a[s2] * l[s2];
  }
  f32x4 acc[8];
#pragma unroll
  for (int i = 0; i < 8; ++i) acc[i] = (f32x4){0.f, 0.f, 0.f, 0.f};
  for (int s2 = 0; s2 < nseg; ++s2) {
    const float* src = po + (size_t)(sid0 + s2) * 8192 + q * 128 + hq * 32;
    const float as = a[s2];
#pragma unroll
    for (int i = 0; i < 8; ++i) {
      f32x4 v = *(const f32x4*)(src + i * 4);
#pragma unroll
      for (int c = 0; c < 4; ++c) acc[i][c] += as * v[c];
    }
  }
  const float inv = 1.0f / lsum;
  float* o = out + ((size_t)(b * T_ + j * 64 + q)) * H_ + hq * 32;
#pragma unroll
  for (int i = 0; i < 8; ++i) {
    f32x4 v;
#pragma unroll
    for (int c = 0; c < 4; ++c) v[c] = acc[i][c] * inv;
    *(f32x4*)(o + i * 4) = v;
  }
}

// ---------------------------------------------------------------------------
extern "C" void kernel_launch(void* const* d_in, const int* in_sizes, int n_in,
                              void* d_out, int out_size, void* d_ws, size_t ws_size,
                              hipStream_t stream) {
  const float* x  = (const float*)d_in[0];
  const float* Wq = (const float*)d_in[1];
  const float* Wk = (const float*)d_in[2];
  const float* Wv = (const float*)d_in[3];
  float* out = (float*)d_out;

  char* ws = (char*)d_ws;
  short* qb  = (short*)(ws);                // 4 MB   q  bf16 [BT][128]
  short* kb  = (short*)(ws + 4194304);      // 4 MB   k  bf16 [BT][128]
  short* vtb = (short*)(ws + 8388608);      // 4 MB   v^T bf16 [B][128][T]
  short* Wt  = (short*)(ws + 12582912);     // 0.75 MB W^T bf16 [3][128][1024]
  float* po  = (float*)(ws + 14680064);     // 20 MB  partial O (640 x 32 KB)
  float* pm  = (float*)(ws + 35651584);     // 160 KB partial m
  float* pl  = (float*)(ws + 35915776);     // 160 KB partial l

  wcvt_kernel<<<dim3(D_ / 64, 3), 256, 0, stream>>>(Wq, Wk, Wv, Wt);
  proj_kernel<<<dim3(BT / 64, 3), 256, 0, stream>>>(x, Wt, qb, kb, vtb);
  attn_part<<<dim3(8 * 80), 256, 0, stream>>>(qb, kb, vtb, po, pm, pl);
  attn_reduce<<<dim3(8 * 32), 256, 0, stream>>>(po, pm, pl, out);
}